// Round 1
// baseline (643.398 us; speedup 1.0000x reference)
//
#include <hip/hip_runtime.h>
#include <math.h>

#define DIM 512
#define NH 8
#define HD 64
#define LSEQ 8192
#define BSZ 16

// Workspace layout (floats):
//   q    : [0,        8192)        16 x 512
//   t    : [8192,     73728)       16 x 8 x 512   (pre-scaled by 0.25)
//   sc   : [73728,    1122304)     16 x 8 x 8192  (scores -> weights in place)
//   part : [1122304,  3219456)     16 x 32 x 4096 (per-chunk partial u)
//   u    : [3219456,  3284992)     16 x 8 x 512
//   ctx  : [3284992,  3293184)     16 x 512

// ---------------- K1a: q = Q @ Wq + bq ----------------
__global__ __launch_bounds__(256) void k_qproj(const float* __restrict__ Q,
        const float* __restrict__ Wq, const float* __restrict__ bq,
        float* __restrict__ q) {
    int b = blockIdx.x >> 1;
    int j = ((blockIdx.x & 1) << 8) + threadIdx.x;
    __shared__ float qs[DIM];
    qs[threadIdx.x]       = Q[b * DIM + threadIdx.x];
    qs[threadIdx.x + 256] = Q[b * DIM + threadIdx.x + 256];
    __syncthreads();
    float acc = bq[j];
    #pragma unroll 8
    for (int i = 0; i < DIM; ++i) acc = fmaf(qs[i], Wq[i * DIM + j], acc);
    q[b * DIM + j] = acc;
}

// ---------------- K1b: t[b,h,i] = 0.25 * sum_j Wk[i, h*64+j] * q[b, h*64+j] ----
// (0.25 = 1/(sqrt(HD)=8) / (TAU=0.5); bk term is constant over l -> dropped,
//  softmax is shift-invariant)
__global__ __launch_bounds__(256) void k_tproj(const float* __restrict__ q,
        const float* __restrict__ Wk, float* __restrict__ t) {
    int b = blockIdx.x >> 4;
    int o = ((blockIdx.x & 15) << 8) + threadIdx.x;
    int h = o >> 9, i = o & 511;
    __shared__ float qs[DIM];
    qs[threadIdx.x]       = q[b * DIM + threadIdx.x];
    qs[threadIdx.x + 256] = q[b * DIM + threadIdx.x + 256];
    __syncthreads();
    const float* wk = Wk + (size_t)i * DIM + h * HD;
    const float* qh = qs + h * HD;
    float a = 0.f;
    #pragma unroll
    for (int j = 0; j < HD; ++j) a = fmaf(wk[j], qh[j], a);
    t[(b * NH + h) * DIM + i] = 0.25f * a;
}

// ---------------- K2: sc[b,h,l] = K[b,l,:] . t[b,h,:] ----------------
// One wave per group of 8 rows; lane owns 8 consecutive K columns.
__global__ __launch_bounds__(256) void k_scores(const float* __restrict__ Kin,
        const float* __restrict__ t, float* __restrict__ sc) {
    int b  = blockIdx.x >> 8;             // 16 b x 256 chunks of 32 rows
    int l0 = (blockIdx.x & 255) << 5;
    int lane = threadIdx.x & 63;
    int wave = threadIdx.x >> 6;
    float4 ta[NH], tb[NH];
    #pragma unroll
    for (int h = 0; h < NH; ++h) {
        const float* tp = t + (b * NH + h) * DIM + lane * 8;
        ta[h] = *(const float4*)tp;
        tb[h] = *(const float4*)(tp + 4);
    }
    int lbase = l0 + wave * 8;
    float keep = 0.f;
    #pragma unroll
    for (int i = 0; i < 8; ++i) {
        const float* kp = Kin + ((size_t)(b * LSEQ + lbase + i)) * DIM + lane * 8;
        float4 ka = *(const float4*)kp;
        float4 kb = *(const float4*)(kp + 4);
        float s[NH];
        #pragma unroll
        for (int h = 0; h < NH; ++h) {
            float p = ka.x * ta[h].x + ka.y * ta[h].y + ka.z * ta[h].z + ka.w * ta[h].w
                    + kb.x * tb[h].x + kb.y * tb[h].y + kb.z * tb[h].z + kb.w * tb[h].w;
            p += __shfl_xor(p, 1);
            p += __shfl_xor(p, 2);
            p += __shfl_xor(p, 4);
            p += __shfl_xor(p, 8);
            p += __shfl_xor(p, 16);
            p += __shfl_xor(p, 32);
            s[h] = p;
        }
        int hh = lane >> 3;
        float sel = s[0];
        sel = (hh == 1) ? s[1] : sel;
        sel = (hh == 2) ? s[2] : sel;
        sel = (hh == 3) ? s[3] : sel;
        sel = (hh == 4) ? s[4] : sel;
        sel = (hh == 5) ? s[5] : sel;
        sel = (hh == 6) ? s[6] : sel;
        sel = (hh == 7) ? s[7] : sel;
        if ((lane & 7) == i) keep = sel;
    }
    int h = lane >> 3, i = lane & 7;
    sc[(size_t)(b * NH + h) * LSEQ + lbase + i] = keep;
}

// ---------------- K3: softmax over l, in place ----------------
__global__ __launch_bounds__(256) void k_softmax(float* __restrict__ sc) {
    float* base = sc + (size_t)blockIdx.x * LSEQ;
    int tid = threadIdx.x;
    int lane = tid & 63, wave = tid >> 6;
    float4 v[8];
    float m = -1e30f;
    #pragma unroll
    for (int k = 0; k < 8; ++k) {
        v[k] = *(const float4*)(base + tid * 4 + k * 1024);
        m = fmaxf(m, fmaxf(fmaxf(v[k].x, v[k].y), fmaxf(v[k].z, v[k].w)));
    }
    #pragma unroll
    for (int d = 1; d < 64; d <<= 1) m = fmaxf(m, __shfl_xor(m, d));
    __shared__ float sm[4], ss[4];
    if (lane == 0) sm[wave] = m;
    __syncthreads();
    m = fmaxf(fmaxf(sm[0], sm[1]), fmaxf(sm[2], sm[3]));
    float sum = 0.f;
    #pragma unroll
    for (int k = 0; k < 8; ++k) {
        v[k].x = __expf(v[k].x - m);
        v[k].y = __expf(v[k].y - m);
        v[k].z = __expf(v[k].z - m);
        v[k].w = __expf(v[k].w - m);
        sum += v[k].x + v[k].y + v[k].z + v[k].w;
    }
    #pragma unroll
    for (int d = 1; d < 64; d <<= 1) sum += __shfl_xor(sum, d);
    if (lane == 0) ss[wave] = sum;
    __syncthreads();
    sum = ss[0] + ss[1] + ss[2] + ss[3];
    float inv = 1.f / sum;
    #pragma unroll
    for (int k = 0; k < 8; ++k) {
        v[k].x *= inv; v[k].y *= inv; v[k].z *= inv; v[k].w *= inv;
        *(float4*)(base + tid * 4 + k * 1024) = v[k];
    }
}

// ---------------- K4: partial u = sum_l w[b,h,l] * V[b,l,:] over a 256-row chunk
__global__ __launch_bounds__(256) void k_vpass(const float* __restrict__ Vin,
        const float* __restrict__ sc, float* __restrict__ part) {
    int b = blockIdx.x >> 5;
    int chunk = blockIdx.x & 31;
    int l0 = chunk << 8;
    int tid = threadIdx.x;
    __shared__ float smem[4096];
    // stage weights transposed: smem[j*8+h]
    #pragma unroll
    for (int idx = tid; idx < 2048; idx += 256) {
        int h = idx >> 8, j = idx & 255;
        smem[j * 8 + h] = sc[(size_t)(b * NH + h) * LSEQ + l0 + j];
    }
    __syncthreads();
    int r = tid >> 7;            // 2 row-teams
    int col = (tid & 127) << 2;  // 4 consecutive cols per thread
    float4 a0 = {0,0,0,0}, a1 = {0,0,0,0}, a2 = {0,0,0,0}, a3 = {0,0,0,0};
    float4 a4 = {0,0,0,0}, a5 = {0,0,0,0}, a6 = {0,0,0,0}, a7 = {0,0,0,0};
    #pragma unroll 4
    for (int j = r; j < 256; j += 2) {
        const float* vp = Vin + ((size_t)(b * LSEQ + l0 + j)) * DIM + col;
        float4 vv = *(const float4*)vp;
        float4 wa = *(const float4*)&smem[j * 8];
        float4 wb = *(const float4*)&smem[j * 8 + 4];
        a0.x = fmaf(wa.x, vv.x, a0.x); a0.y = fmaf(wa.x, vv.y, a0.y);
        a0.z = fmaf(wa.x, vv.z, a0.z); a0.w = fmaf(wa.x, vv.w, a0.w);
        a1.x = fmaf(wa.y, vv.x, a1.x); a1.y = fmaf(wa.y, vv.y, a1.y);
        a1.z = fmaf(wa.y, vv.z, a1.z); a1.w = fmaf(wa.y, vv.w, a1.w);
        a2.x = fmaf(wa.z, vv.x, a2.x); a2.y = fmaf(wa.z, vv.y, a2.y);
        a2.z = fmaf(wa.z, vv.z, a2.z); a2.w = fmaf(wa.z, vv.w, a2.w);
        a3.x = fmaf(wa.w, vv.x, a3.x); a3.y = fmaf(wa.w, vv.y, a3.y);
        a3.z = fmaf(wa.w, vv.z, a3.z); a3.w = fmaf(wa.w, vv.w, a3.w);
        a4.x = fmaf(wb.x, vv.x, a4.x); a4.y = fmaf(wb.x, vv.y, a4.y);
        a4.z = fmaf(wb.x, vv.z, a4.z); a4.w = fmaf(wb.x, vv.w, a4.w);
        a5.x = fmaf(wb.y, vv.x, a5.x); a5.y = fmaf(wb.y, vv.y, a5.y);
        a5.z = fmaf(wb.y, vv.z, a5.z); a5.w = fmaf(wb.y, vv.w, a5.w);
        a6.x = fmaf(wb.z, vv.x, a6.x); a6.y = fmaf(wb.z, vv.y, a6.y);
        a6.z = fmaf(wb.z, vv.z, a6.z); a6.w = fmaf(wb.z, vv.w, a6.w);
        a7.x = fmaf(wb.w, vv.x, a7.x); a7.y = fmaf(wb.w, vv.y, a7.y);
        a7.z = fmaf(wb.w, vv.z, a7.z); a7.w = fmaf(wb.w, vv.w, a7.w);
    }
    __syncthreads();
    if (r == 1) {
        *(float4*)&smem[0 * DIM + col] = a0; *(float4*)&smem[1 * DIM + col] = a1;
        *(float4*)&smem[2 * DIM + col] = a2; *(float4*)&smem[3 * DIM + col] = a3;
        *(float4*)&smem[4 * DIM + col] = a4; *(float4*)&smem[5 * DIM + col] = a5;
        *(float4*)&smem[6 * DIM + col] = a6; *(float4*)&smem[7 * DIM + col] = a7;
    }
    __syncthreads();
    if (r == 0) {
        float* pout = part + (size_t)(b * 32 + chunk) * 4096;
        float4 o;
        #define EMIT(H, A) \
            o = *(const float4*)&smem[H * DIM + col]; \
            o.x += A.x; o.y += A.y; o.z += A.z; o.w += A.w; \
            *(float4*)&pout[H * DIM + col] = o;
        EMIT(0, a0) EMIT(1, a1) EMIT(2, a2) EMIT(3, a3)
        EMIT(4, a4) EMIT(5, a5) EMIT(6, a6) EMIT(7, a7)
        #undef EMIT
    }
}

// ---------------- K4b: u = sum over 32 chunk partials ----------------
__global__ __launch_bounds__(256) void k_ureduce(const float* __restrict__ part,
        float* __restrict__ u) {
    int o = blockIdx.x * 256 + threadIdx.x;  // 65536 outputs
    int b = o >> 12, rr = o & 4095;
    float s = 0.f;
    #pragma unroll 8
    for (int c = 0; c < 32; ++c) s += part[(size_t)(b * 32 + c) * 4096 + rr];
    u[o] = s;
}

// ---------------- K5a: ctx[b,j] = u[b, j/64, :] . Wv[:, j] + bv[j] ----------------
__global__ __launch_bounds__(256) void k_ctx(const float* __restrict__ u,
        const float* __restrict__ Wv, const float* __restrict__ bv,
        float* __restrict__ ctx) {
    int b = blockIdx.x >> 1;
    int j = ((blockIdx.x & 1) << 8) + threadIdx.x;
    __shared__ float us[4096];
    for (int idx = threadIdx.x; idx < 4096; idx += 256) us[idx] = u[b * 4096 + idx];
    __syncthreads();
    int h = j >> 6;
    const float* uh = us + h * DIM;
    float a = bv[j];
    #pragma unroll 8
    for (int i = 0; i < DIM; ++i) a = fmaf(uh[i], Wv[(size_t)i * DIM + j], a);
    ctx[b * DIM + j] = a;
}

// ---------------- K5b: out = LN(ctx @ Wo + bo)*gamma+beta + Q ----------------
__global__ __launch_bounds__(256) void k_out(const float* __restrict__ ctx,
        const float* __restrict__ Wo, const float* __restrict__ bo,
        const float* __restrict__ gamma, const float* __restrict__ beta,
        const float* __restrict__ Qin, float* __restrict__ out) {
    int b = blockIdx.x;
    int tid = threadIdx.x;
    __shared__ float cs[DIM];
    cs[tid]       = ctx[b * DIM + tid];
    cs[tid + 256] = ctx[b * DIM + tid + 256];
    __syncthreads();
    float o0 = bo[tid], o1 = bo[tid + 256];
    #pragma unroll 8
    for (int m = 0; m < DIM; ++m) {
        float c = cs[m];
        o0 = fmaf(c, Wo[m * DIM + tid], o0);
        o1 = fmaf(c, Wo[m * DIM + tid + 256], o1);
    }
    float s = o0 + o1, sq = o0 * o0 + o1 * o1;
    #pragma unroll
    for (int d = 1; d < 64; d <<= 1) { s += __shfl_xor(s, d); sq += __shfl_xor(sq, d); }
    __shared__ float rs[4], rq[4];
    int lane = tid & 63, wave = tid >> 6;
    if (lane == 0) { rs[wave] = s; rq[wave] = sq; }
    __syncthreads();
    s  = rs[0] + rs[1] + rs[2] + rs[3];
    sq = rq[0] + rq[1] + rq[2] + rq[3];
    float mu = s * (1.f / DIM);
    float var = sq * (1.f / DIM) - mu * mu;
    float rstd = rsqrtf(var + 1e-5f);
    int j0 = tid, j1 = tid + 256;
    out[b * DIM + j0] = (o0 - mu) * rstd * gamma[j0] + beta[j0] + Qin[b * DIM + j0];
    out[b * DIM + j1] = (o1 - mu) * rstd * gamma[j1] + beta[j1] + Qin[b * DIM + j1];
}

extern "C" void kernel_launch(void* const* d_in, const int* in_sizes, int n_in,
                              void* d_out, int out_size, void* d_ws, size_t ws_size,
                              hipStream_t stream) {
    const float* Q     = (const float*)d_in[0];
    const float* K     = (const float*)d_in[1];
    const float* V     = (const float*)d_in[2];
    const float* Wq    = (const float*)d_in[3];
    const float* bq    = (const float*)d_in[4];
    const float* Wk    = (const float*)d_in[5];
    // d_in[6] = bk: provably unused (adds an l-invariant constant to scores;
    // softmax is shift-invariant)
    const float* Wv    = (const float*)d_in[7];
    const float* bv    = (const float*)d_in[8];
    const float* Wo    = (const float*)d_in[9];
    const float* bo    = (const float*)d_in[10];
    const float* gamma = (const float*)d_in[11];
    const float* beta  = (const float*)d_in[12];
    float* ws   = (float*)d_ws;
    float* q    = ws;
    float* t    = ws + 8192;
    float* sc   = ws + 73728;
    float* part = ws + 1122304;
    float* u    = ws + 3219456;
    float* ctx  = ws + 3284992;
    float* out  = (float*)d_out;

    k_qproj  <<<32,   256, 0, stream>>>(Q, Wq, bq, q);
    k_tproj  <<<256,  256, 0, stream>>>(q, Wk, t);
    k_scores <<<4096, 256, 0, stream>>>(K, t, sc);
    k_softmax<<<128,  256, 0, stream>>>(sc);
    k_vpass  <<<512,  256, 0, stream>>>(V, sc, part);
    k_ureduce<<<256,  256, 0, stream>>>(part, u);
    k_ctx    <<<32,   256, 0, stream>>>(u, Wv, bv, ctx);
    k_out    <<<16,   256, 0, stream>>>(ctx, Wo, bo, gamma, beta, Q, out);
}

// Round 2
// 574.553 us; speedup vs baseline: 1.1198x; 1.1198x over previous
//
#include <hip/hip_runtime.h>
#include <math.h>

#define DIM 512
#define NH 8
#define HD 64
#define LSEQ 8192
#define BSZ 16
#define CHUNK 128
#define NCH 64            // LSEQ / CHUNK
#define PSTRIDE 4112      // 8*512 u + 8 m + 8 s  (16B-aligned stride)

// ws layout (floats):
//   t_g  : [0,       65536)     16 x 8 x 512   (pre-scaled by 0.25)
//   part : [65536,   4276224)   16 x 64 x 4112
//   ctx  : [4276224, 4284416)   16 x 512
//   po   : [4284416, 4349952)   16 x 8 x 512   (split-K partials of out proj)

// ---------- KA: per (b,h): q_head = Q@Wq_head + bq_head ; t = 0.25*Wk_head·q_head
// bk dropped: adds an l-invariant constant to scores; softmax is shift-invariant.
__global__ __launch_bounds__(256) void k_qt(const float* __restrict__ Q,
        const float* __restrict__ Wq, const float* __restrict__ bq,
        const float* __restrict__ Wk, float* __restrict__ t_g) {
    int b = blockIdx.x >> 3, h = blockIdx.x & 7;
    int tid = threadIdx.x;
    __shared__ __align__(16) float qs[DIM];
    __shared__ __align__(16) float partial[256];
    __shared__ __align__(16) float qh[HD];
    qs[tid]       = Q[b * DIM + tid];
    qs[tid + 256] = Q[b * DIM + tid + 256];
    __syncthreads();
    int jj = tid & 63, ks = tid >> 6;
    {
        float a = 0.f;
        const float* wp = Wq + (size_t)(ks * 128) * DIM + h * HD + jj;
        const float* qp = qs + ks * 128;
        #pragma unroll 8
        for (int i = 0; i < 128; ++i) a = fmaf(qp[i], wp[(size_t)i * DIM], a);
        partial[tid] = a;
    }
    __syncthreads();
    if (tid < 64)
        qh[tid] = partial[tid] + partial[tid + 64] + partial[tid + 128] +
                  partial[tid + 192] + bq[h * HD + tid];
    __syncthreads();
    #pragma unroll
    for (int rep = 0; rep < 2; ++rep) {
        int i = tid + rep * 256;
        const float4* wk = (const float4*)(Wk + (size_t)i * DIM + h * HD);
        float a = 0.f;
        #pragma unroll
        for (int v = 0; v < 16; ++v) {
            float4 w4 = wk[v];
            a = fmaf(w4.x, qh[v * 4 + 0], a);
            a = fmaf(w4.y, qh[v * 4 + 1], a);
            a = fmaf(w4.z, qh[v * 4 + 2], a);
            a = fmaf(w4.w, qh[v * 4 + 3], a);
        }
        t_g[(size_t)(b * NH + h) * DIM + i] = 0.25f * a;
    }
}

// ---------- KB: fused scores -> local softmax (online) -> weighted V, per 128-row chunk
__global__ __launch_bounds__(256) void k_attn(const float* __restrict__ Kin,
        const float* __restrict__ Vin, const float* __restrict__ t_g,
        float* __restrict__ part) {
    int b = blockIdx.x >> 6, chunk = blockIdx.x & 63;
    int tid = threadIdx.x, lane = tid & 63, w = tid >> 6;
    __shared__ __align__(16) float e_lds[CHUNK * 8];   // [row*8 + h]
    __shared__ __align__(16) float vstage[8 * DIM];
    __shared__ float wred[32];                         // [w*8 + h] max
    __shared__ float wsum[32];                         // [w*8 + h] sum
    // t fragments: lane owns cols lane*8 .. lane*8+7 for all 8 heads
    float4 ta[8], tb[8];
    #pragma unroll
    for (int h = 0; h < 8; ++h) {
        const float* tp = t_g + (size_t)(b * NH + h) * DIM + lane * 8;
        ta[h] = *(const float4*)tp;
        tb[h] = *(const float4*)(tp + 4);
    }
    const size_t rowbase = (size_t)(b * LSEQ + chunk * CHUNK);
    // ---- phase 1: scores for this wave's 32 rows (4 groups of 8)
    for (int g = 0; g < 4; ++g) {
        int r0 = w * 32 + g * 8;
        float keep = 0.f;
        #pragma unroll
        for (int i = 0; i < 8; ++i) {
            const float* kp = Kin + (rowbase + r0 + i) * DIM + lane * 8;
            float4 ka = *(const float4*)kp;
            float4 kb = *(const float4*)(kp + 4);
            float s[8];
            #pragma unroll
            for (int h = 0; h < 8; ++h) {
                float p = ka.x * ta[h].x + ka.y * ta[h].y + ka.z * ta[h].z + ka.w * ta[h].w
                        + kb.x * tb[h].x + kb.y * tb[h].y + kb.z * tb[h].z + kb.w * tb[h].w;
                p += __shfl_xor(p, 1);
                p += __shfl_xor(p, 2);
                p += __shfl_xor(p, 4);
                p += __shfl_xor(p, 8);
                p += __shfl_xor(p, 16);
                p += __shfl_xor(p, 32);
                s[h] = p;
            }
            int hh = lane >> 3;
            float sel = s[0];
            sel = (hh == 1) ? s[1] : sel;
            sel = (hh == 2) ? s[2] : sel;
            sel = (hh == 3) ? s[3] : sel;
            sel = (hh == 4) ? s[4] : sel;
            sel = (hh == 5) ? s[5] : sel;
            sel = (hh == 6) ? s[6] : sel;
            sel = (hh == 7) ? s[7] : sel;
            if ((lane & 7) == i) keep = sel;
        }
        e_lds[(r0 + (lane & 7)) * 8 + (lane >> 3)] = keep;
    }
    __syncthreads();
    // ---- phase 2: per-head local max, exp, sum (thread t owns head t&7, rows (t>>3)*4..+4)
    int h2 = tid & 7, rb = (tid >> 3) * 4;
    float x0 = e_lds[(rb + 0) * 8 + h2], x1 = e_lds[(rb + 1) * 8 + h2];
    float x2 = e_lds[(rb + 2) * 8 + h2], x3 = e_lds[(rb + 3) * 8 + h2];
    float mx = fmaxf(fmaxf(x0, x1), fmaxf(x2, x3));
    mx = fmaxf(mx, __shfl_xor(mx, 8));
    mx = fmaxf(mx, __shfl_xor(mx, 16));
    mx = fmaxf(mx, __shfl_xor(mx, 32));
    if (lane < 8) wred[w * 8 + lane] = mx;
    __syncthreads();
    float m = fmaxf(fmaxf(wred[h2], wred[8 + h2]), fmaxf(wred[16 + h2], wred[24 + h2]));
    float e0 = __expf(x0 - m), e1 = __expf(x1 - m);
    float e2 = __expf(x2 - m), e3 = __expf(x3 - m);
    e_lds[(rb + 0) * 8 + h2] = e0;
    e_lds[(rb + 1) * 8 + h2] = e1;
    e_lds[(rb + 2) * 8 + h2] = e2;
    e_lds[(rb + 3) * 8 + h2] = e3;
    float sm = e0 + e1 + e2 + e3;
    sm += __shfl_xor(sm, 8);
    sm += __shfl_xor(sm, 16);
    sm += __shfl_xor(sm, 32);
    if (lane < 8) wsum[w * 8 + lane] = sm;
    __syncthreads();
    // ---- phase 3: u_partial[h][:] = sum_j e[j][h] * V[row j][:]
    int r = tid >> 7, col = (tid & 127) << 2;
    float4 a0 = {0,0,0,0}, a1 = {0,0,0,0}, a2 = {0,0,0,0}, a3 = {0,0,0,0};
    float4 a4 = {0,0,0,0}, a5 = {0,0,0,0}, a6 = {0,0,0,0}, a7 = {0,0,0,0};
    #pragma unroll 4
    for (int j = r; j < CHUNK; j += 2) {
        const float* vp = Vin + (rowbase + j) * DIM + col;
        float4 vv = *(const float4*)vp;
        float4 wa = *(const float4*)&e_lds[j * 8];
        float4 wb = *(const float4*)&e_lds[j * 8 + 4];
        a0.x = fmaf(wa.x, vv.x, a0.x); a0.y = fmaf(wa.x, vv.y, a0.y);
        a0.z = fmaf(wa.x, vv.z, a0.z); a0.w = fmaf(wa.x, vv.w, a0.w);
        a1.x = fmaf(wa.y, vv.x, a1.x); a1.y = fmaf(wa.y, vv.y, a1.y);
        a1.z = fmaf(wa.y, vv.z, a1.z); a1.w = fmaf(wa.y, vv.w, a1.w);
        a2.x = fmaf(wa.z, vv.x, a2.x); a2.y = fmaf(wa.z, vv.y, a2.y);
        a2.z = fmaf(wa.z, vv.z, a2.z); a2.w = fmaf(wa.z, vv.w, a2.w);
        a3.x = fmaf(wa.w, vv.x, a3.x); a3.y = fmaf(wa.w, vv.y, a3.y);
        a3.z = fmaf(wa.w, vv.z, a3.z); a3.w = fmaf(wa.w, vv.w, a3.w);
        a4.x = fmaf(wb.x, vv.x, a4.x); a4.y = fmaf(wb.x, vv.y, a4.y);
        a4.z = fmaf(wb.x, vv.z, a4.z); a4.w = fmaf(wb.x, vv.w, a4.w);
        a5.x = fmaf(wb.y, vv.x, a5.x); a5.y = fmaf(wb.y, vv.y, a5.y);
        a5.z = fmaf(wb.y, vv.z, a5.z); a5.w = fmaf(wb.y, vv.w, a5.w);
        a6.x = fmaf(wb.z, vv.x, a6.x); a6.y = fmaf(wb.z, vv.y, a6.y);
        a6.z = fmaf(wb.z, vv.z, a6.z); a6.w = fmaf(wb.z, vv.w, a6.w);
        a7.x = fmaf(wb.w, vv.x, a7.x); a7.y = fmaf(wb.w, vv.y, a7.y);
        a7.z = fmaf(wb.w, vv.z, a7.z); a7.w = fmaf(wb.w, vv.w, a7.w);
    }
    __syncthreads();
    if (r == 1) {
        *(float4*)&vstage[0 * DIM + col] = a0; *(float4*)&vstage[1 * DIM + col] = a1;
        *(float4*)&vstage[2 * DIM + col] = a2; *(float4*)&vstage[3 * DIM + col] = a3;
        *(float4*)&vstage[4 * DIM + col] = a4; *(float4*)&vstage[5 * DIM + col] = a5;
        *(float4*)&vstage[6 * DIM + col] = a6; *(float4*)&vstage[7 * DIM + col] = a7;
    }
    __syncthreads();
    float* pout = part + (size_t)(b * NCH + chunk) * PSTRIDE;
    if (r == 0) {
        float4 o;
        #define EMIT(H, A) \
            o = *(const float4*)&vstage[H * DIM + col]; \
            o.x += A.x; o.y += A.y; o.z += A.z; o.w += A.w; \
            *(float4*)&pout[H * DIM + col] = o;
        EMIT(0, a0) EMIT(1, a1) EMIT(2, a2) EMIT(3, a3)
        EMIT(4, a4) EMIT(5, a5) EMIT(6, a6) EMIT(7, a7)
        #undef EMIT
    }
    if (tid < 8) {
        float mm = fmaxf(fmaxf(wred[tid], wred[8 + tid]), fmaxf(wred[16 + tid], wred[24 + tid]));
        pout[4096 + tid] = mm;
        pout[4104 + tid] = wsum[tid] + wsum[8 + tid] + wsum[16 + tid] + wsum[24 + tid];
    }
}

// ---------- KC: per (b,h): combine chunk partials (rescale), then ctx = u @ Wv_headcols + bv
__global__ __launch_bounds__(256) void k_uctx(const float* __restrict__ part,
        const float* __restrict__ Wv, const float* __restrict__ bv,
        float* __restrict__ ctx) {
    int b = blockIdx.x >> 3, h = blockIdx.x & 7;
    int tid = threadIdx.x;
    __shared__ __align__(16) float alphas[NCH];
    __shared__ __align__(16) float u_lds[DIM];
    __shared__ __align__(16) float red4[256];
    __shared__ float sinv_s;
    if (tid < 64) {
        const float* pm = part + (size_t)(b * NCH + tid) * PSTRIDE;
        float mv = pm[4096 + h], sv = pm[4104 + h];
        float M = mv;
        #pragma unroll
        for (int d = 1; d < 64; d <<= 1) M = fmaxf(M, __shfl_xor(M, d));
        float al = __expf(mv - M);
        alphas[tid] = al;
        float c = al * sv;
        #pragma unroll
        for (int d = 1; d < 64; d <<= 1) c += __shfl_xor(c, d);
        if (tid == 0) sinv_s = 1.f / c;
    }
    __syncthreads();
    float sinv = sinv_s;
    float u0 = 0.f, u1 = 0.f;
    #pragma unroll 4
    for (int c = 0; c < NCH; ++c) {
        const float* pu = part + (size_t)(b * NCH + c) * PSTRIDE + h * DIM;
        float al = alphas[c];
        u0 = fmaf(al, pu[tid], u0);
        u1 = fmaf(al, pu[tid + 256], u1);
    }
    u_lds[tid]       = u0 * sinv;
    u_lds[tid + 256] = u1 * sinv;
    __syncthreads();
    int jj = tid & 63, ks = tid >> 6;
    float a = 0.f;
    const float* wp = Wv + (size_t)(ks * 128) * DIM + h * HD + jj;
    const float* up = u_lds + ks * 128;
    #pragma unroll 8
    for (int i = 0; i < 128; ++i) a = fmaf(up[i], wp[(size_t)i * DIM], a);
    red4[tid] = a;
    __syncthreads();
    if (tid < 64)
        ctx[b * DIM + h * HD + tid] = red4[tid] + red4[tid + 64] +
            red4[tid + 128] + red4[tid + 192] + bv[h * HD + tid];
}

// ---------- KD: split-K partials of out = ctx @ Wo  (k-slice of 64 per block)
__global__ __launch_bounds__(256) void k_oproj(const float* __restrict__ ctx,
        const float* __restrict__ Wo, float* __restrict__ po) {
    int b = blockIdx.x >> 3, ks = blockIdx.x & 7;
    int tid = threadIdx.x;
    __shared__ float cs[64];
    if (tid < 64) cs[tid] = ctx[b * DIM + ks * 64 + tid];
    __syncthreads();
    float a0 = 0.f, a1 = 0.f;
    const float* wp = Wo + (size_t)(ks * 64) * DIM;
    #pragma unroll 8
    for (int i = 0; i < 64; ++i) {
        float c = cs[i];
        a0 = fmaf(c, wp[(size_t)i * DIM + tid], a0);
        a1 = fmaf(c, wp[(size_t)i * DIM + tid + 256], a1);
    }
    po[(size_t)(b * 8 + ks) * DIM + tid]       = a0;
    po[(size_t)(b * 8 + ks) * DIM + tid + 256] = a1;
}

// ---------- KE: out = LN(sum_ks po + bo)*gamma + beta + Q
__global__ __launch_bounds__(256) void k_ln(const float* __restrict__ po,
        const float* __restrict__ bo, const float* __restrict__ gamma,
        const float* __restrict__ beta, const float* __restrict__ Qin,
        float* __restrict__ out) {
    int b = blockIdx.x, tid = threadIdx.x;
    float o0 = bo[tid], o1 = bo[tid + 256];
    #pragma unroll
    for (int ks = 0; ks < 8; ++ks) {
        o0 += po[(size_t)(b * 8 + ks) * DIM + tid];
        o1 += po[(size_t)(b * 8 + ks) * DIM + tid + 256];
    }
    float s = o0 + o1, sq = o0 * o0 + o1 * o1;
    #pragma unroll
    for (int d = 1; d < 64; d <<= 1) { s += __shfl_xor(s, d); sq += __shfl_xor(sq, d); }
    __shared__ float rs[4], rq[4];
    int lane = tid & 63, wave = tid >> 6;
    if (lane == 0) { rs[wave] = s; rq[wave] = sq; }
    __syncthreads();
    s  = rs[0] + rs[1] + rs[2] + rs[3];
    sq = rq[0] + rq[1] + rq[2] + rq[3];
    float mu = s * (1.f / DIM);
    float var = sq * (1.f / DIM) - mu * mu;
    float rstd = rsqrtf(var + 1e-5f);
    int j0 = tid, j1 = tid + 256;
    out[b * DIM + j0] = (o0 - mu) * rstd * gamma[j0] + beta[j0] + Qin[b * DIM + j0];
    out[b * DIM + j1] = (o1 - mu) * rstd * gamma[j1] + beta[j1] + Qin[b * DIM + j1];
}

extern "C" void kernel_launch(void* const* d_in, const int* in_sizes, int n_in,
                              void* d_out, int out_size, void* d_ws, size_t ws_size,
                              hipStream_t stream) {
    const float* Q     = (const float*)d_in[0];
    const float* K     = (const float*)d_in[1];
    const float* V     = (const float*)d_in[2];
    const float* Wq    = (const float*)d_in[3];
    const float* bq    = (const float*)d_in[4];
    const float* Wk    = (const float*)d_in[5];
    // d_in[6] = bk: unused (l-invariant shift; softmax is shift-invariant)
    const float* Wv    = (const float*)d_in[7];
    const float* bv    = (const float*)d_in[8];
    const float* Wo    = (const float*)d_in[9];
    const float* bo    = (const float*)d_in[10];
    const float* gamma = (const float*)d_in[11];
    const float* beta  = (const float*)d_in[12];
    float* ws   = (float*)d_ws;
    float* t_g  = ws;
    float* part = ws + 65536;
    float* ctx  = ws + 4276224;
    float* po   = ws + 4284416;
    float* out  = (float*)d_out;

    k_qt   <<<128,  256, 0, stream>>>(Q, Wq, bq, Wk, t_g);
    k_attn <<<1024, 256, 0, stream>>>(K, V, t_g, part);
    k_uctx <<<128,  256, 0, stream>>>(part, Wv, bv, ctx);
    k_oproj<<<128,  256, 0, stream>>>(ctx, Wo, po);
    k_ln   <<<16,   256, 0, stream>>>(po, bo, gamma, beta, Q, out);
}